// Round 1
// baseline (1074.413 us; speedup 1.0000x reference)
//
#include <hip/hip_runtime.h>
#include <math.h>

#define Bsz 4
#define Cch 128
#define Hh 128
#define Ww 128
#define HW (Hh * Ww)

// ---------------- Kernel T: transpose x [B][C][H][W] -> xt [B][HW][C] ----------
__global__ __launch_bounds__(256) void transpose_x(const float* __restrict__ x,
                                                   float* __restrict__ xt) {
    __shared__ float tile[32][33];
    int b  = blockIdx.z;
    int c0 = blockIdx.y * 32;
    int p0 = blockIdx.x * 32;
    int tx = threadIdx.x;  // 0..31
    int ty = threadIdx.y;  // 0..7
    const float* xb  = x  + (size_t)b * Cch * HW;
    float*       xtb = xt + (size_t)b * HW * Cch;
    #pragma unroll
    for (int i = 0; i < 32; i += 8) {
        int c = c0 + ty + i;
        tile[ty + i][tx] = xb[(size_t)c * HW + p0 + tx];
    }
    __syncthreads();
    #pragma unroll
    for (int i = 0; i < 32; i += 8) {
        int p = p0 + ty + i;
        xtb[(size_t)p * Cch + c0 + tx] = tile[tx][ty + i];
    }
}

// ---------------- Kernel W: w_def [O][C][3][3] -> wt [k][c][o] -----------------
__global__ __launch_bounds__(256) void transpose_w(const float* __restrict__ w_def,
                                                   float* __restrict__ wt) {
    int idx = blockIdx.x * 256 + threadIdx.x;
    if (idx >= 9 * 128 * 128) return;
    int o = idx & 127;
    int c = (idx >> 7) & 127;
    int k = idx >> 14;
    wt[idx] = w_def[(o * 128 + c) * 9 + k];
}

// ---------------- Kernel O: offset conv (18ch 3x3, pad 1) ----------------------
// off stored as [p][18], p = b*HW + h*W + w
__global__ __launch_bounds__(256) void offset_conv(const float* __restrict__ x,
                                                   const float* __restrict__ w_off,
                                                   const float* __restrict__ b_off,
                                                   float* __restrict__ off) {
    int p  = blockIdx.x * 256 + threadIdx.x;  // 0..65535
    int b  = p >> 14;
    int hw = p & 16383;
    int h  = hw >> 7;
    int w  = hw & 127;
    const float* xb = x + (size_t)b * Cch * HW;

    float acc[18];
    #pragma unroll
    for (int o = 0; o < 18; ++o) acc[o] = b_off[o];

    for (int c = 0; c < Cch; ++c) {
        const float* xc = xb + (size_t)c * HW;
        float xv[9];
        #pragma unroll
        for (int ky = 0; ky < 3; ++ky) {
            int  y  = h + ky - 1;
            bool vy = (y >= 0) && (y < Hh);
            int  yc = min(max(y, 0), Hh - 1);
            #pragma unroll
            for (int kx = 0; kx < 3; ++kx) {
                int  xx = w + kx - 1;
                bool vx = (xx >= 0) && (xx < Ww);
                int  xc2 = min(max(xx, 0), Ww - 1);
                float v = xc[yc * Ww + xc2];
                xv[ky * 3 + kx] = (vy && vx) ? v : 0.0f;
            }
        }
        #pragma unroll
        for (int o = 0; o < 18; ++o) {
            #pragma unroll
            for (int t = 0; t < 9; ++t)
                acc[o] = fmaf(xv[t], w_off[(o * Cch + c) * 9 + t], acc[o]);
        }
    }
    float* op = off + (size_t)p * 18;
    #pragma unroll
    for (int o = 0; o < 18; ++o) op[o] = acc[o];
}

// ---------------- Kernel M: fused gather + einsum + attention ------------------
// One block (128 threads) per (b,h) image row. Thread = pixel (w) in einsum phase.
// LDS: sampled_k [128 px][128 c] fp32, XOR-swizzled (c ^ (px&31)) -> 2 lanes/bank.
__global__ __launch_bounds__(128) void main_fused(const float* __restrict__ xt,
                                                  const float* __restrict__ wt,
                                                  const float* __restrict__ off,
                                                  const float* __restrict__ b_def,
                                                  const float* __restrict__ w_attn,
                                                  const float* __restrict__ b_attn,
                                                  float* __restrict__ out) {
    __shared__ float smp[128 * 128];  // 64 KiB exactly
    int blk = blockIdx.x;  // b*128 + h
    int b   = blk >> 7;
    int h   = blk & 127;
    int tid = threadIdx.x;  // 0..127

    const float* xtb  = xt  + (size_t)b * HW * Cch;
    const float* offp = off + ((size_t)(b * HW + h * Ww)) * 18;

    float acc[128];
    #pragma unroll
    for (int o = 0; o < 128; ++o) acc[o] = b_def[o];

    int pxs = tid >> 4;  // 0..7
    int cb  = tid & 15;  // 0..15

    for (int k = 0; k < 9; ++k) {
        int ky = k / 3, kx = k - ky * 3;
        // ---- gather phase: 16 iters x (8 px x 16 c-lanes), 8 c's per lane ----
        for (int it = 0; it < 16; ++it) {
            int   px = it * 8 + pxs;  // = w coordinate
            float dy = offp[px * 18 + 2 * k];
            float dx = offp[px * 18 + 2 * k + 1];
            float ys = (float)(h - 1 + ky) + dy;
            float xs = (float)(px - 1 + kx) + dx;
            float y0f = floorf(ys), x0f = floorf(xs);
            float wy = ys - y0f, wx = xs - x0f;
            int y0 = (int)y0f, x0 = (int)x0f;
            bool vy0 = (y0 >= 0) && (y0 < Hh);
            bool vy1 = (y0 + 1 >= 0) && (y0 + 1 < Hh);
            bool vx0 = (x0 >= 0) && (x0 < Ww);
            bool vx1 = (x0 + 1 >= 0) && (x0 + 1 < Ww);
            int y0c = min(max(y0, 0), Hh - 1), y1c = min(max(y0 + 1, 0), Hh - 1);
            int x0c = min(max(x0, 0), Ww - 1), x1c = min(max(x0 + 1, 0), Ww - 1);
            const float* r00 = xtb + ((size_t)(y0c * Ww + x0c)) * Cch;
            const float* r01 = xtb + ((size_t)(y0c * Ww + x1c)) * Cch;
            const float* r10 = xtb + ((size_t)(y1c * Ww + x0c)) * Cch;
            const float* r11 = xtb + ((size_t)(y1c * Ww + x1c)) * Cch;
            float w00 = (vy0 && vx0) ? (1.0f - wy) * (1.0f - wx) : 0.0f;
            float w01 = (vy0 && vx1) ? (1.0f - wy) * wx : 0.0f;
            float w10 = (vy1 && vx0) ? wy * (1.0f - wx) : 0.0f;
            float w11 = (vy1 && vx1) ? wy * wx : 0.0f;
            int sw = px & 31;
            #pragma unroll
            for (int j = 0; j < 8; ++j) {
                int c = cb + j * 16;
                float v = w00 * r00[c] + w01 * r01[c] + w10 * r10[c] + w11 * r11[c];
                smp[px * 128 + (c ^ sw)] = v;
            }
        }
        __syncthreads();
        // ---- einsum phase: thread = px, accumulate all 128 output channels ----
        const float* wk   = wt + (size_t)k * 128 * 128;  // wt[k][c][o]
        const float* srow = smp + tid * 128;
        int swz = tid & 31;
        for (int c = 0; c < 128; ++c) {
            float s = srow[c ^ swz];
            const float* wc = wk + c * 128;  // uniform -> scalar loads
            #pragma unroll
            for (int o = 0; o < 128; ++o)
                acc[o] = fmaf(s, wc[o], acc[o]);
        }
        __syncthreads();
    }

    // ---- epilogue: attention gate + sigmoid + relu ----
    float attn = b_attn[0];
    #pragma unroll
    for (int o = 0; o < 128; ++o) attn = fmaf(acc[o], w_attn[o], attn);
    float sig = 1.0f / (1.0f + expf(-attn));
    float* outp = out + (size_t)b * 128 * HW + h * Ww + tid;  // out[b][o][h][w]
    #pragma unroll
    for (int o = 0; o < 128; ++o) {
        float v = acc[o] * sig;
        outp[(size_t)o * HW] = fmaxf(v, 0.0f);
    }
}

// ---------------- launch -------------------------------------------------------
extern "C" void kernel_launch(void* const* d_in, const int* in_sizes, int n_in,
                              void* d_out, int out_size, void* d_ws, size_t ws_size,
                              hipStream_t stream) {
    const float* x      = (const float*)d_in[0];
    const float* w_off  = (const float*)d_in[1];
    const float* b_off  = (const float*)d_in[2];
    const float* w_def  = (const float*)d_in[3];
    const float* b_def  = (const float*)d_in[4];
    const float* w_attn = (const float*)d_in[5];
    const float* b_attn = (const float*)d_in[6];
    float* out = (float*)d_out;

    char*  ws  = (char*)d_ws;
    float* xt  = (float*)ws;                               // 33,554,432 B
    float* wt  = (float*)(ws + 33554432);                  //    589,824 B
    float* off = (float*)(ws + 33554432 + 589824);         //  4,718,592 B

    transpose_x<<<dim3(512, 4, 4), dim3(32, 8), 0, stream>>>(x, xt);
    transpose_w<<<576, 256, 0, stream>>>(w_def, wt);
    offset_conv<<<256, 256, 0, stream>>>(x, w_off, b_off, off);
    main_fused<<<512, 128, 0, stream>>>(xt, wt, off, b_def, w_attn, b_attn, out);
}

// Round 2
// 262.565 us; speedup vs baseline: 4.0920x; 4.0920x over previous
//
#include <hip/hip_runtime.h>
#include <math.h>

#define Bsz 4
#define Cch 128
#define Hh 128
#define Ww 128
#define HW (Hh * Ww)

typedef __attribute__((ext_vector_type(8))) short short8;
typedef __attribute__((ext_vector_type(4))) float float4v;
typedef __attribute__((ext_vector_type(4))) unsigned int uint4v;

__device__ __forceinline__ unsigned short f2bf(float f) {
    unsigned u = __float_as_uint(f);
    return (unsigned short)((u + 0x8000u) >> 16);
}
__device__ __forceinline__ float bflo(unsigned u) { return __uint_as_float(u << 16); }
__device__ __forceinline__ float bfhi(unsigned u) { return __uint_as_float(u & 0xffff0000u); }
__device__ __forceinline__ unsigned packbf2(float lo, float hi) {
    unsigned a = __float_as_uint(lo), b = __float_as_uint(hi);
    return ((a + 0x8000u) >> 16) | ((b + 0x8000u) & 0xffff0000u);
}

// ---- K1: x [B][C][H][W] fp32 -> xt [B][HW][C] bf16 ---------------------------
__global__ __launch_bounds__(256) void transpose_x_bf16(const float* __restrict__ x,
                                                        unsigned short* __restrict__ xt) {
    __shared__ float tile[32][33];
    int b  = blockIdx.z;
    int c0 = blockIdx.y * 32;
    int p0 = blockIdx.x * 32;
    int tx = threadIdx.x, ty = threadIdx.y;
    const float* xb = x + (size_t)b * Cch * HW;
    unsigned short* xtb = xt + (size_t)b * HW * Cch;
    #pragma unroll
    for (int i = 0; i < 32; i += 8)
        tile[ty + i][tx] = xb[(size_t)(c0 + ty + i) * HW + p0 + tx];
    __syncthreads();
    #pragma unroll
    for (int i = 0; i < 32; i += 8)
        xtb[(size_t)(p0 + ty + i) * Cch + c0 + tx] = f2bf(tile[tx][ty + i]);
}

// ---- K2: build B-fragment-linear weight layouts (bf16) -----------------------
// wfragB  [k][q][t(8)][lane(64)][j(8)] : B[c=32q+8*(lane>>4)+j][o=16t+(lane&15)]
// wfragOff[k][q][t(2)][lane(64)][j(8)] : same, o padded 18->32
#define NFB (9 * 4 * 8 * 64 * 8)
#define NFO (9 * 4 * 2 * 64 * 8)
__global__ __launch_bounds__(256) void build_frags(const float* __restrict__ w_def,
                                                   const float* __restrict__ w_off,
                                                   unsigned short* __restrict__ wfB,
                                                   unsigned short* __restrict__ wfO) {
    int idx = blockIdx.x * 256 + threadIdx.x;
    if (idx < NFB) {
        int j = idx & 7, lane = (idx >> 3) & 63, t = (idx >> 9) & 7;
        int q = (idx >> 12) & 3, k = idx >> 14;
        int c = 32 * q + 8 * (lane >> 4) + j;
        int o = 16 * t + (lane & 15);
        wfB[idx] = f2bf(w_def[(size_t)(o * Cch + c) * 9 + k]);
    } else if (idx < NFB + NFO) {
        int i2 = idx - NFB;
        int j = i2 & 7, lane = (i2 >> 3) & 63, t = (i2 >> 9) & 1;
        int q = (i2 >> 10) & 3, k = i2 >> 12;
        int c = 32 * q + 8 * (lane >> 4) + j;
        int o = 16 * t + (lane & 15);
        wfO[i2] = (o < 18) ? f2bf(w_off[(size_t)(o * Cch + c) * 9 + k]) : (unsigned short)0;
    }
}

// ---- K3: offset conv via MFMA, A-frags direct from global xt -----------------
// block = 1 image row (128 px), 256 threads = 4 waves; wave: 32px x 32o(18 valid)
__global__ __launch_bounds__(256) void offset_mfma(const unsigned short* __restrict__ xt,
                                                   const unsigned short* __restrict__ wfO,
                                                   const float* __restrict__ b_off,
                                                   float* __restrict__ off) {
    int blk  = blockIdx.x;           // b*128 + h
    int b    = blk >> 7;
    int h    = blk & 127;
    int tid  = threadIdx.x;
    int wave = tid >> 6;
    int lane = tid & 63;
    int p0   = blk * 128;            // global pixel base (row start)
    int col  = lane & 15;
    int s    = lane >> 4;

    float4v acc[2][2];
    #pragma unroll
    for (int pt = 0; pt < 2; ++pt)
        #pragma unroll
        for (int t = 0; t < 2; ++t) {
            int o = 16 * t + col;
            float bv = (o < 18) ? b_off[o] : 0.0f;
            acc[pt][t] = (float4v){bv, bv, bv, bv};
        }

    const unsigned short* xtb = xt + (size_t)b * HW * Cch;

    for (int k = 0; k < 9; ++k) {
        int y = h + (k / 3) - 1;
        if (y < 0 || y >= Hh) continue;          // uniform: tap contributes zero
        int dxk = (k % 3) - 1;
        #pragma unroll
        for (int q = 0; q < 4; ++q) {
            short8 a[2];
            #pragma unroll
            for (int pt = 0; pt < 2; ++pt) {
                int px = 32 * wave + 16 * pt + col;   // = w coordinate
                int xs = px + dxk;
                bool valid = (xs >= 0) && (xs < Ww);
                int xc = min(max(xs, 0), Ww - 1);
                const short8* ap = (const short8*)(xtb + ((size_t)(y * Ww + xc) * Cch + 32 * q + 8 * s));
                short8 av = *ap;
                if (!valid) av = (short8)0;
                a[pt] = av;
            }
            #pragma unroll
            for (int t = 0; t < 2; ++t) {
                short8 bv = *(const short8*)(wfO + ((size_t)((k * 4 + q) * 2 + t) * 64 + lane) * 8);
                #pragma unroll
                for (int pt = 0; pt < 2; ++pt)
                    acc[pt][t] = __builtin_amdgcn_mfma_f32_16x16x32_bf16(a[pt], bv, acc[pt][t], 0, 0, 0);
            }
        }
    }
    #pragma unroll
    for (int pt = 0; pt < 2; ++pt)
        #pragma unroll
        for (int t = 0; t < 2; ++t) {
            int o = 16 * t + col;
            if (o < 18) {
                #pragma unroll
                for (int r = 0; r < 4; ++r) {
                    int px = 32 * wave + 16 * pt + 4 * s + r;
                    off[(size_t)(p0 + px) * 18 + o] = acc[pt][t][r];
                }
            }
        }
}

// ---- K4: main fused gather + MFMA einsum + attention -------------------------
// block = 1 image row (128 px), 256 threads = 4 waves; wave: 32px x 128o
#define SMPITCH 136  // ushorts per px row (128 + 8 pad) -> 272 B
__global__ __launch_bounds__(256) void main_mfma(const unsigned short* __restrict__ xt,
                                                 const unsigned short* __restrict__ wfB,
                                                 const float* __restrict__ off,
                                                 const float* __restrict__ b_def,
                                                 const float* __restrict__ w_attn,
                                                 const float* __restrict__ b_attn,
                                                 float* __restrict__ out) {
    __shared__ unsigned short smp[128 * SMPITCH];  // 34 KiB
    int blk  = blockIdx.x;   // b*128 + h
    int b    = blk >> 7;
    int h    = blk & 127;
    int tid  = threadIdx.x;
    int wave = tid >> 6;
    int lane = tid & 63;
    int p0   = blk * 128;
    int col  = lane & 15;
    int s    = lane >> 4;

    const unsigned short* xtb = xt + (size_t)b * HW * Cch;

    float4v acc[2][8];
    #pragma unroll
    for (int pt = 0; pt < 2; ++pt)
        #pragma unroll
        for (int t = 0; t < 8; ++t) {
            float bv = b_def[16 * t + col];
            acc[pt][t] = (float4v){bv, bv, bv, bv};
        }

    float wA[8];
    #pragma unroll
    for (int t = 0; t < 8; ++t) wA[t] = w_attn[16 * t + col];

    int gpx = tid >> 1;        // gather px (w coord), 2 threads per px
    int c0  = (tid & 1) * 64;  // each handles 64 channels

    for (int k = 0; k < 9; ++k) {
        int ky = k / 3, kx = k % 3;
        // ---------------- gather tap k into LDS ----------------
        {
            float dy = off[(size_t)(p0 + gpx) * 18 + 2 * k];
            float dx = off[(size_t)(p0 + gpx) * 18 + 2 * k + 1];
            float ys = (float)(h - 1 + ky) + dy;
            float xs = (float)(gpx - 1 + kx) + dx;
            float y0f = floorf(ys), x0f = floorf(xs);
            float wy = ys - y0f, wx = xs - x0f;
            int y0 = (int)y0f, x0 = (int)x0f;
            bool vy0 = (y0 >= 0) && (y0 < Hh);
            bool vy1 = (y0 + 1 >= 0) && (y0 + 1 < Hh);
            bool vx0 = (x0 >= 0) && (x0 < Ww);
            bool vx1 = (x0 + 1 >= 0) && (x0 + 1 < Ww);
            int y0c = min(max(y0, 0), Hh - 1), y1c = min(max(y0 + 1, 0), Hh - 1);
            int x0c = min(max(x0, 0), Ww - 1), x1c = min(max(x0 + 1, 0), Ww - 1);
            float w00 = (vy0 && vx0) ? (1.0f - wy) * (1.0f - wx) : 0.0f;
            float w01 = (vy0 && vx1) ? (1.0f - wy) * wx : 0.0f;
            float w10 = (vy1 && vx0) ? wy * (1.0f - wx) : 0.0f;
            float w11 = (vy1 && vx1) ? wy * wx : 0.0f;
            size_t b00 = (size_t)(y0c * Ww + x0c) * Cch + c0;
            size_t b01 = (size_t)(y0c * Ww + x1c) * Cch + c0;
            size_t b10 = (size_t)(y1c * Ww + x0c) * Cch + c0;
            size_t b11 = (size_t)(y1c * Ww + x1c) * Cch + c0;
            #pragma unroll
            for (int g = 0; g < 8; ++g) {
                int cc = 8 * g;
                uint4v u00 = *(const uint4v*)(xtb + b00 + cc);
                uint4v u01 = *(const uint4v*)(xtb + b01 + cc);
                uint4v u10 = *(const uint4v*)(xtb + b10 + cc);
                uint4v u11 = *(const uint4v*)(xtb + b11 + cc);
                uint4v res;
                #pragma unroll
                for (int e = 0; e < 4; ++e) {
                    float lo = w00 * bflo(u00[e]);
                    lo = fmaf(w01, bflo(u01[e]), lo);
                    lo = fmaf(w10, bflo(u10[e]), lo);
                    lo = fmaf(w11, bflo(u11[e]), lo);
                    float hi = w00 * bfhi(u00[e]);
                    hi = fmaf(w01, bfhi(u01[e]), hi);
                    hi = fmaf(w10, bfhi(u10[e]), hi);
                    hi = fmaf(w11, bfhi(u11[e]), hi);
                    res[e] = packbf2(lo, hi);
                }
                *(uint4v*)(&smp[gpx * SMPITCH + c0 + cc]) = res;
            }
        }
        __syncthreads();
        // ---------------- MFMA tap k ----------------
        #pragma unroll
        for (int q = 0; q < 4; ++q) {
            short8 a[2];
            #pragma unroll
            for (int pt = 0; pt < 2; ++pt) {
                int px = 32 * wave + 16 * pt + col;
                a[pt] = *(const short8*)(&smp[px * SMPITCH + 32 * q + 8 * s]);
            }
            #pragma unroll
            for (int t = 0; t < 8; ++t) {
                short8 bv = *(const short8*)(wfB + ((size_t)((k * 4 + q) * 8 + t) * 64 + lane) * 8);
                #pragma unroll
                for (int pt = 0; pt < 2; ++pt)
                    acc[pt][t] = __builtin_amdgcn_mfma_f32_16x16x32_bf16(a[pt], bv, acc[pt][t], 0, 0, 0);
            }
        }
        __syncthreads();
    }

    // ---------------- epilogue: attention gate + sigmoid + relu ----------------
    float battn = b_attn[0];
    #pragma unroll
    for (int pt = 0; pt < 2; ++pt) {
        float sig[4];
        #pragma unroll
        for (int r = 0; r < 4; ++r) {
            float pr = 0.0f;
            #pragma unroll
            for (int t = 0; t < 8; ++t) pr = fmaf(acc[pt][t][r], wA[t], pr);
            #pragma unroll
            for (int m = 1; m < 16; m <<= 1) pr += __shfl_xor(pr, m, 64);
            float attn = pr + battn;
            sig[r] = 1.0f / (1.0f + expf(-attn));
        }
        #pragma unroll
        for (int t = 0; t < 8; ++t) {
            int o = 16 * t + col;
            #pragma unroll
            for (int r = 0; r < 4; ++r) {
                int px = 32 * wave + 16 * pt + 4 * s + r;
                float v = acc[pt][t][r] * sig[r];
                out[((size_t)(b * Cch + o)) * HW + h * Ww + px] = fmaxf(v, 0.0f);
            }
        }
    }
}

// ---- launch ------------------------------------------------------------------
extern "C" void kernel_launch(void* const* d_in, const int* in_sizes, int n_in,
                              void* d_out, int out_size, void* d_ws, size_t ws_size,
                              hipStream_t stream) {
    const float* x      = (const float*)d_in[0];
    const float* w_off  = (const float*)d_in[1];
    const float* b_off  = (const float*)d_in[2];
    const float* w_def  = (const float*)d_in[3];
    const float* b_def  = (const float*)d_in[4];
    const float* w_attn = (const float*)d_in[5];
    const float* b_attn = (const float*)d_in[6];
    float* out = (float*)d_out;

    char* ws = (char*)d_ws;
    unsigned short* xt  = (unsigned short*)ws;                       // 16,777,216 B
    unsigned short* wfB = (unsigned short*)(ws + 16777216);          //    294,912 B
    unsigned short* wfO = (unsigned short*)(ws + 17072128);          //     73,728 B
    float*          off = (float*)(ws + 17145856);                   //  4,718,592 B

    transpose_x_bf16<<<dim3(512, 4, 4), dim3(32, 8), 0, stream>>>(x, xt);
    build_frags<<<720, 256, 0, stream>>>(w_def, w_off, wfB, wfO);
    offset_mfma<<<512, 256, 0, stream>>>(xt, wfO, b_off, off);
    main_mfma<<<512, 256, 0, stream>>>(xt, wfB, off, b_def, w_attn, b_attn, out);
}

// Round 3
// 222.873 us; speedup vs baseline: 4.8207x; 1.1781x over previous
//
#include <hip/hip_runtime.h>
#include <math.h>

#define Cch 128
#define Hh 128
#define Ww 128
#define HW (Hh * Ww)

typedef __attribute__((ext_vector_type(8))) short short8;
typedef __attribute__((ext_vector_type(4))) float float4v;
typedef __attribute__((ext_vector_type(4))) unsigned int uint4v;

__device__ __forceinline__ unsigned short f2bf(float f) {
    unsigned u = __float_as_uint(f);
    return (unsigned short)((u + 0x8000u) >> 16);
}
__device__ __forceinline__ float bflo(unsigned u) { return __uint_as_float(u << 16); }
__device__ __forceinline__ float bfhi(unsigned u) { return __uint_as_float(u & 0xffff0000u); }
__device__ __forceinline__ unsigned packbf2(float lo, float hi) {
    unsigned a = __float_as_uint(lo), b = __float_as_uint(hi);
    return ((a + 0x8000u) >> 16) | ((b + 0x8000u) & 0xffff0000u);
}

// ---- K1: x [B][C][H][W] fp32 -> xt [B][HW][C] bf16 ---------------------------
__global__ __launch_bounds__(256) void transpose_x_bf16(const float* __restrict__ x,
                                                        unsigned short* __restrict__ xt) {
    __shared__ float tile[32][33];
    int b  = blockIdx.z;
    int c0 = blockIdx.y * 32;
    int p0 = blockIdx.x * 32;
    int tx = threadIdx.x, ty = threadIdx.y;
    const float* xb = x + (size_t)b * Cch * HW;
    unsigned short* xtb = xt + (size_t)b * HW * Cch;
    #pragma unroll
    for (int i = 0; i < 32; i += 8)
        tile[ty + i][tx] = xb[(size_t)(c0 + ty + i) * HW + p0 + tx];
    __syncthreads();
    #pragma unroll
    for (int i = 0; i < 32; i += 8)
        xtb[(size_t)(p0 + ty + i) * Cch + c0 + tx] = f2bf(tile[tx][ty + i]);
}

// ---- K2: build B-fragment-linear weight layouts (bf16) -----------------------
// wfragB  [k][q][t(8)][lane(64)][j(8)] : B[c=32q+8*(lane>>4)+j][o=16t+(lane&15)]
// wfragOff[k][q][t(2)][lane(64)][j(8)] : same, o padded 18->32
#define NFB (9 * 4 * 8 * 64 * 8)
#define NFO (9 * 4 * 2 * 64 * 8)
__global__ __launch_bounds__(256) void build_frags(const float* __restrict__ w_def,
                                                   const float* __restrict__ w_off,
                                                   unsigned short* __restrict__ wfB,
                                                   unsigned short* __restrict__ wfO) {
    int idx = blockIdx.x * 256 + threadIdx.x;
    if (idx < NFB) {
        int j = idx & 7, lane = (idx >> 3) & 63, t = (idx >> 9) & 7;
        int q = (idx >> 12) & 3, k = idx >> 14;
        int c = 32 * q + 8 * (lane >> 4) + j;
        int o = 16 * t + (lane & 15);
        wfB[idx] = f2bf(w_def[(size_t)(o * Cch + c) * 9 + k]);
    } else if (idx < NFB + NFO) {
        int i2 = idx - NFB;
        int j = i2 & 7, lane = (i2 >> 3) & 63, t = (i2 >> 9) & 1;
        int q = (i2 >> 10) & 3, k = i2 >> 12;
        int c = 32 * q + 8 * (lane >> 4) + j;
        int o = 16 * t + (lane & 15);
        wfO[i2] = (o < 18) ? f2bf(w_off[(size_t)(o * Cch + c) * 9 + k]) : (unsigned short)0;
    }
}

// ---- block -> (b, h, w0) mapping with XCD pinning ----------------------------
// 2048 blocks; heuristic blockIdx%8 = XCD. Two XCDs per batch image so each
// XCD's 4 MiB L2 holds exactly one 4 MiB bf16 image.
__device__ __forceinline__ void blk_map(int blk, int& b, int& h, int& w0) {
    int xcd = blk & 7;
    b = xcd >> 1;
    int seg = ((xcd & 1) << 8) | (blk >> 3);  // 0..511
    h  = seg >> 2;
    w0 = (seg & 3) << 5;
}

// ---- K3: offset conv via MFMA, 1 wave/block, A direct from global ------------
// wave: 32 px x 32 o (18 valid)
__global__ __launch_bounds__(64, 4) void offset_direct(const unsigned short* __restrict__ xt,
                                                       const unsigned short* __restrict__ wfO,
                                                       const float* __restrict__ b_off,
                                                       float* __restrict__ off) {
    int b, h, w0;
    blk_map(blockIdx.x, b, h, w0);
    int lane = threadIdx.x;
    int col  = lane & 15;
    int s    = lane >> 4;

    const unsigned short* xtb = xt + (size_t)b * HW * Cch;

    float4v acc[2][2];
    #pragma unroll
    for (int pt = 0; pt < 2; ++pt)
        #pragma unroll
        for (int t = 0; t < 2; ++t) {
            int o = 16 * t + col;
            float bv = (o < 18) ? b_off[o] : 0.0f;
            acc[pt][t] = (float4v){bv, bv, bv, bv};
        }

    for (int k = 0; k < 9; ++k) {
        int y = h + (k / 3) - 1;
        if (y < 0 || y >= Hh) continue;  // uniform across block
        int dxk = (k % 3) - 1;
        int  ofs[2];
        bool val[2];
        #pragma unroll
        for (int pt = 0; pt < 2; ++pt) {
            int px = w0 + 16 * pt + col;
            int xs = px + dxk;
            val[pt] = (xs >= 0) && (xs < Ww);
            int xc  = min(max(xs, 0), Ww - 1);
            ofs[pt] = (y * Ww + xc) * Cch + 8 * s;
        }
        #pragma unroll
        for (int q = 0; q < 4; ++q) {
            short8 a[2];
            #pragma unroll
            for (int pt = 0; pt < 2; ++pt) {
                short8 av = *(const short8*)(xtb + ofs[pt] + 32 * q);
                if (!val[pt]) av = (short8)0;
                a[pt] = av;
            }
            #pragma unroll
            for (int t = 0; t < 2; ++t) {
                short8 bv = *(const short8*)(wfO + ((size_t)((k * 4 + q) * 2 + t) * 64 + lane) * 8);
                #pragma unroll
                for (int pt = 0; pt < 2; ++pt)
                    acc[pt][t] = __builtin_amdgcn_mfma_f32_16x16x32_bf16(a[pt], bv, acc[pt][t], 0, 0, 0);
            }
        }
    }
    #pragma unroll
    for (int pt = 0; pt < 2; ++pt)
        #pragma unroll
        for (int t = 0; t < 2; ++t) {
            int o = 16 * t + col;
            if (o < 18) {
                #pragma unroll
                for (int r = 0; r < 4; ++r) {
                    int px = w0 + 16 * pt + 4 * s + r;
                    off[((size_t)(b * HW + h * Ww + px)) * 18 + o] = acc[pt][t][r];
                }
            }
        }
}

// ---- K4: main fused: direct-to-register bilinear gather + MFMA + attention ---
// 1 wave/block, wave: 32 px x 128 o; no LDS, no barriers.
__global__ __launch_bounds__(64, 3) void main_direct(const unsigned short* __restrict__ xt,
                                                     const unsigned short* __restrict__ wfB,
                                                     const float* __restrict__ off,
                                                     const float* __restrict__ b_def,
                                                     const float* __restrict__ w_attn,
                                                     const float* __restrict__ b_attn,
                                                     float* __restrict__ out) {
    int b, h, w0;
    blk_map(blockIdx.x, b, h, w0);
    int lane = threadIdx.x;
    int col  = lane & 15;
    int s    = lane >> 4;

    const unsigned short* xtb = xt + (size_t)b * HW * Cch;

    float4v acc[2][8];
    #pragma unroll
    for (int pt = 0; pt < 2; ++pt)
        #pragma unroll
        for (int t = 0; t < 8; ++t) {
            float bv = b_def[16 * t + col];
            acc[pt][t] = (float4v){bv, bv, bv, bv};
        }

    for (int k = 0; k < 9; ++k) {
        int ky = k / 3, kx = k % 3;
        // per-pt bilinear setup: 4 corner offsets + 4 weights, per lane's px
        int   o00[2], o01[2], o10[2], o11[2];
        float w00[2], w01[2], w10[2], w11[2];
        #pragma unroll
        for (int pt = 0; pt < 2; ++pt) {
            int px = w0 + 16 * pt + col;
            size_t gp = (size_t)(b * HW + h * Ww + px);
            float dy = off[gp * 18 + 2 * k];
            float dx = off[gp * 18 + 2 * k + 1];
            float ys = (float)(h - 1 + ky) + dy;
            float xs = (float)(px - 1 + kx) + dx;
            float y0f = floorf(ys), x0f = floorf(xs);
            float wy = ys - y0f, wx = xs - x0f;
            int y0 = (int)y0f, x0 = (int)x0f;
            bool vy0 = (y0 >= 0) && (y0 < Hh);
            bool vy1 = (y0 + 1 >= 0) && (y0 + 1 < Hh);
            bool vx0 = (x0 >= 0) && (x0 < Ww);
            bool vx1 = (x0 + 1 >= 0) && (x0 + 1 < Ww);
            int y0c = min(max(y0, 0), Hh - 1), y1c = min(max(y0 + 1, 0), Hh - 1);
            int x0c = min(max(x0, 0), Ww - 1), x1c = min(max(x0 + 1, 0), Ww - 1);
            w00[pt] = (vy0 && vx0) ? (1.0f - wy) * (1.0f - wx) : 0.0f;
            w01[pt] = (vy0 && vx1) ? (1.0f - wy) * wx : 0.0f;
            w10[pt] = (vy1 && vx0) ? wy * (1.0f - wx) : 0.0f;
            w11[pt] = (vy1 && vx1) ? wy * wx : 0.0f;
            o00[pt] = (y0c * Ww + x0c) * Cch + 8 * s;
            o01[pt] = (y0c * Ww + x1c) * Cch + 8 * s;
            o10[pt] = (y1c * Ww + x0c) * Cch + 8 * s;
            o11[pt] = (y1c * Ww + x1c) * Cch + 8 * s;
        }
        #pragma unroll
        for (int q = 0; q < 4; ++q) {
            short8 a[2];
            #pragma unroll
            for (int pt = 0; pt < 2; ++pt) {
                uint4v u00 = *(const uint4v*)(xtb + o00[pt] + 32 * q);
                uint4v u01 = *(const uint4v*)(xtb + o01[pt] + 32 * q);
                uint4v u10 = *(const uint4v*)(xtb + o10[pt] + 32 * q);
                uint4v u11 = *(const uint4v*)(xtb + o11[pt] + 32 * q);
                uint4v res;
                #pragma unroll
                for (int e = 0; e < 4; ++e) {
                    float lo = w00[pt] * bflo(u00[e]);
                    lo = fmaf(w01[pt], bflo(u01[e]), lo);
                    lo = fmaf(w10[pt], bflo(u10[e]), lo);
                    lo = fmaf(w11[pt], bflo(u11[e]), lo);
                    float hi = w00[pt] * bfhi(u00[e]);
                    hi = fmaf(w01[pt], bfhi(u01[e]), hi);
                    hi = fmaf(w10[pt], bfhi(u10[e]), hi);
                    hi = fmaf(w11[pt], bfhi(u11[e]), hi);
                    res[e] = packbf2(lo, hi);
                }
                a[pt] = *(short8*)&res;
            }
            #pragma unroll
            for (int t = 0; t < 8; ++t) {
                short8 bv = *(const short8*)(wfB + ((size_t)((k * 4 + q) * 8 + t) * 64 + lane) * 8);
                #pragma unroll
                for (int pt = 0; pt < 2; ++pt)
                    acc[pt][t] = __builtin_amdgcn_mfma_f32_16x16x32_bf16(a[pt], bv, acc[pt][t], 0, 0, 0);
            }
        }
    }

    // ---- epilogue: attention gate + sigmoid + relu ----
    float wA[8];
    #pragma unroll
    for (int t = 0; t < 8; ++t) wA[t] = w_attn[16 * t + col];
    float battn = b_attn[0];
    #pragma unroll
    for (int pt = 0; pt < 2; ++pt) {
        float sig[4];
        #pragma unroll
        for (int r = 0; r < 4; ++r) {
            float pr = 0.0f;
            #pragma unroll
            for (int t = 0; t < 8; ++t) pr = fmaf(acc[pt][t][r], wA[t], pr);
            #pragma unroll
            for (int m = 1; m < 16; m <<= 1) pr += __shfl_xor(pr, m, 64);
            sig[r] = 1.0f / (1.0f + expf(-(pr + battn)));
        }
        #pragma unroll
        for (int t = 0; t < 8; ++t) {
            int o = 16 * t + col;
            #pragma unroll
            for (int r = 0; r < 4; ++r) {
                int px = w0 + 16 * pt + 4 * s + r;
                float v = acc[pt][t][r] * sig[r];
                out[((size_t)(b * Cch + o)) * HW + h * Ww + px] = fmaxf(v, 0.0f);
            }
        }
    }
}

// ---- launch ------------------------------------------------------------------
extern "C" void kernel_launch(void* const* d_in, const int* in_sizes, int n_in,
                              void* d_out, int out_size, void* d_ws, size_t ws_size,
                              hipStream_t stream) {
    const float* x      = (const float*)d_in[0];
    const float* w_off  = (const float*)d_in[1];
    const float* b_off  = (const float*)d_in[2];
    const float* w_def  = (const float*)d_in[3];
    const float* b_def  = (const float*)d_in[4];
    const float* w_attn = (const float*)d_in[5];
    const float* b_attn = (const float*)d_in[6];
    float* out = (float*)d_out;

    char* ws = (char*)d_ws;
    unsigned short* xt  = (unsigned short*)ws;                       // 16,777,216 B
    unsigned short* wfB = (unsigned short*)(ws + 16777216);          //    294,912 B
    unsigned short* wfO = (unsigned short*)(ws + 17072128);          //     73,728 B
    float*          off = (float*)(ws + 17145856);                   //  4,718,592 B

    transpose_x_bf16<<<dim3(512, 4, 4), dim3(32, 8), 0, stream>>>(x, xt);
    build_frags<<<720, 256, 0, stream>>>(w_def, w_off, wfB, wfO);
    offset_direct<<<2048, 64, 0, stream>>>(xt, wfO, b_off, off);
    main_direct<<<2048, 64, 0, stream>>>(xt, wfB, off, b_def, w_attn, b_attn, out);
}